// Round 10
// baseline (433.037 us; speedup 1.0000x reference)
//
#include <hip/hip_runtime.h>
#include <hip/hip_bf16.h>
#include <math.h>

// Problem constants
#define BATCH 1024
#define NREAL 784
#define NPAD  896      // 7*128 zero-padded graph dim (k-dim of G3)
#define NPADM 1024     // 8*128 zero-padded adjacency ROW dim (m-dim of G3)
#define C1D   32
#define C2D   32
#define HDIM  512
#define NCLS  10
#define KFC   25088    // 784*32

#define KS_G1 7        // split-K G1: K=896 -> 128/slice, 4 iters (EVEN)
#define KS_FC 14       // split-K fc1: K=25088 -> 1792/slice, 56 iters (EVEN)

#define BK 32

using bf16x8  = __attribute__((ext_vector_type(8))) __bf16;
using floatx4 = __attribute__((ext_vector_type(4))) float;

__device__ __forceinline__ float elu_f(float t) {
    return t > 0.f ? t : (__expf(t) - 1.f);
}

// LDS-only barrier: waits ds ops but leaves global loads (vmcnt) in flight.
__device__ __forceinline__ void wg_barrier_lds() {
    asm volatile("s_waitcnt lgkmcnt(0)\n\ts_barrier" ::: "memory");
}

// ---------------------------------------------------------------------------
// r5 BT-GEMM (proven): register-staged + XOR-swizzled LDS (0 conflicts).
// C[row][col] = sum_k A[row][k]*Bm[col][k]; kIters even.
// 128x128 tile, 4 waves 2x2 of 64x64. fp32 partial store (G1, G4).
// ---------------------------------------------------------------------------
__launch_bounds__(256)
__global__ void gemm_bt(const __hip_bfloat16* __restrict__ A, int lda,
                        const __hip_bfloat16* __restrict__ Bm, int ldb,
                        int kIters, int kPerZ, size_t sliceStride,
                        float* __restrict__ outF, int ldc)
{
    __shared__ __align__(16) __hip_bfloat16 As[2][128 * BK];
    __shared__ __align__(16) __hip_bfloat16 Bs[2][128 * BK];

    const int tid  = threadIdx.x;
    const int lane = tid & 63;
    const int wave = tid >> 6;
    const int wi = wave >> 1, wj = wave & 1;

    const int m0 = blockIdx.y * 128;
    const int n0 = blockIdx.x * 128;
    const int kBase = blockIdx.z * kPerZ;

    const int rowInChunk = lane >> 2;
    const int kOff8 = (lane & 3) * 8;

    const __hip_bfloat16* aSrc0 = A  + (size_t)(m0 + (wave * 2 + 0) * 16 + rowInChunk) * lda + kBase + kOff8;
    const __hip_bfloat16* aSrc1 = A  + (size_t)(m0 + (wave * 2 + 1) * 16 + rowInChunk) * lda + kBase + kOff8;
    const __hip_bfloat16* bSrc0 = Bm + (size_t)(n0 + (wave * 2 + 0) * 16 + rowInChunk) * ldb + kBase + kOff8;
    const __hip_bfloat16* bSrc1 = Bm + (size_t)(n0 + (wave * 2 + 1) * 16 + rowInChunk) * ldb + kBase + kOff8;

    const int wSlot = (((lane & 3) + ((lane >> 3) & 3)) & 3) * 8;
    const int ldsW0 = (wave * 2 + 0) * 512 + rowInChunk * 32 + wSlot;
    const int ldsW1 = ldsW0 + 512;

    const int rSlot = ((((lane >> 4) + (((lane & 15) >> 1) & 3)) & 3)) * 8;
    const int rRow  = lane & 15;

    floatx4 acc[4][4];
    const floatx4 zero4 = {0.f, 0.f, 0.f, 0.f};
    #pragma unroll
    for (int i = 0; i < 4; i++)
        #pragma unroll
        for (int j = 0; j < 4; j++) acc[i][j] = zero4;

    int4 aAe0, aAe1, bAe0, bAe1;
    int4 aAo0, aAo1, bAo0, bAo1;

    aAe0 = *(const int4*)aSrc0; aAe1 = *(const int4*)aSrc1;
    bAe0 = *(const int4*)bSrc0; bAe1 = *(const int4*)bSrc1;
    aSrc0 += BK; aSrc1 += BK; bSrc0 += BK; bSrc1 += BK;
    aAo0 = *(const int4*)aSrc0; aAo1 = *(const int4*)aSrc1;
    bAo0 = *(const int4*)bSrc0; bAo1 = *(const int4*)bSrc1;
    aSrc0 += BK; aSrc1 += BK; bSrc0 += BK; bSrc1 += BK;

    *(int4*)(&As[0][ldsW0]) = aAe0;
    *(int4*)(&As[0][ldsW1]) = aAe1;
    *(int4*)(&Bs[0][ldsW0]) = bAe0;
    *(int4*)(&Bs[0][ldsW1]) = bAe1;
    wg_barrier_lds();

    for (int kt = 0; kt < kIters; kt += 2) {
        const bool more = (kt + 2 < kIters);

        {   // u = 0
            bf16x8 af[4], bfr[4];
            #pragma unroll
            for (int mi = 0; mi < 4; mi++)
                af[mi] = *(const bf16x8*)(&As[0][(wi * 64 + mi * 16 + rRow) * BK + rSlot]);
            #pragma unroll
            for (int nj = 0; nj < 4; nj++)
                bfr[nj] = *(const bf16x8*)(&Bs[0][(wj * 64 + nj * 16 + rRow) * BK + rSlot]);

            if (more) {
                aAe0 = *(const int4*)aSrc0; aAe1 = *(const int4*)aSrc1;
                bAe0 = *(const int4*)bSrc0; bAe1 = *(const int4*)bSrc1;
                aSrc0 += BK; aSrc1 += BK; bSrc0 += BK; bSrc1 += BK;
            }
            *(int4*)(&As[1][ldsW0]) = aAo0;
            *(int4*)(&As[1][ldsW1]) = aAo1;
            *(int4*)(&Bs[1][ldsW0]) = bAo0;
            *(int4*)(&Bs[1][ldsW1]) = bAo1;

            #pragma unroll
            for (int mi = 0; mi < 4; mi++)
                #pragma unroll
                for (int nj = 0; nj < 4; nj++)
                    acc[mi][nj] = __builtin_amdgcn_mfma_f32_16x16x32_bf16(af[mi], bfr[nj], acc[mi][nj], 0, 0, 0);

            wg_barrier_lds();
        }

        {   // u = 1
            bf16x8 af[4], bfr[4];
            #pragma unroll
            for (int mi = 0; mi < 4; mi++)
                af[mi] = *(const bf16x8*)(&As[1][(wi * 64 + mi * 16 + rRow) * BK + rSlot]);
            #pragma unroll
            for (int nj = 0; nj < 4; nj++)
                bfr[nj] = *(const bf16x8*)(&Bs[1][(wj * 64 + nj * 16 + rRow) * BK + rSlot]);

            if (more) {
                aAo0 = *(const int4*)aSrc0; aAo1 = *(const int4*)aSrc1;
                bAo0 = *(const int4*)bSrc0; bAo1 = *(const int4*)bSrc1;
                aSrc0 += BK; aSrc1 += BK; bSrc0 += BK; bSrc1 += BK;
                *(int4*)(&As[0][ldsW0]) = aAe0;
                *(int4*)(&As[0][ldsW1]) = aAe1;
                *(int4*)(&Bs[0][ldsW0]) = bAe0;
                *(int4*)(&Bs[0][ldsW1]) = bAe1;
            }

            #pragma unroll
            for (int mi = 0; mi < 4; mi++)
                #pragma unroll
                for (int nj = 0; nj < 4; nj++)
                    acc[mi][nj] = __builtin_amdgcn_mfma_f32_16x16x32_bf16(af[mi], bfr[nj], acc[mi][nj], 0, 0, 0);

            wg_barrier_lds();
        }
    }

    #pragma unroll
    for (int mi = 0; mi < 4; mi++) {
        #pragma unroll
        for (int nj = 0; nj < 4; nj++) {
            #pragma unroll
            for (int r = 0; r < 4; r++) {
                const int row = m0 + wi * 64 + mi * 16 + (lane >> 4) * 4 + r;
                const int col = n0 + wj * 64 + nj * 16 + (lane & 15);
                outF[(size_t)blockIdx.z * sliceStride + (size_t)row * ldc + col] = acc[mi][nj][r];
            }
        }
    }
}

// ---------------------------------------------------------------------------
// G3 kernel: 256(m) x 128(n) per block — TWO 128-row m-tiles accumulate
// against ONE staged B tile, halving B's LLC re-reads (my: 7 -> 4 with rows
// padded to 1024). 4 waves 2x2; each wave owns two 64x64 tiles (m and m+128).
// 32 MFMA per barrier. r5 swizzle/staging; kIters even.
// Epilogue: elu(acc+bias[col&31]) -> bf16 outH[(col>>5)*KFC+row*32+(col&31)],
// masked to row < 784 (covers the 896..1023 pad rows too).
// ---------------------------------------------------------------------------
__launch_bounds__(256, 2)
__global__ void gemm_g3(const __hip_bfloat16* __restrict__ Ar,   // [1024][896]
                        const __hip_bfloat16* __restrict__ Tt,   // [32768][896]
                        int kIters,
                        __hip_bfloat16* __restrict__ outH,
                        const float* __restrict__ bias)
{
    __shared__ __align__(16) __hip_bfloat16 As[2][256 * BK];   // 16 KB each
    __shared__ __align__(16) __hip_bfloat16 Bs[2][128 * BK];   //  8 KB each

    const int tid  = threadIdx.x;
    const int lane = tid & 63;
    const int wave = tid >> 6;
    const int wi = wave >> 1, wj = wave & 1;

    const int m0 = blockIdx.y * 256;   // y in [0,4)
    const int n0 = blockIdx.x * 128;   // x in [0,256)

    const int rowInChunk = lane >> 2;
    const int kOff8 = (lane & 3) * 8;

    // A: 16 chunks of 16 rows; wave stages chunks 4w..4w+3
    const __hip_bfloat16* aSrc[4];
    #pragma unroll
    for (int c = 0; c < 4; c++)
        aSrc[c] = Ar + (size_t)(m0 + (wave * 4 + c) * 16 + rowInChunk) * NPAD + kOff8;
    // B: 8 chunks; wave stages chunks 2w..2w+1
    const __hip_bfloat16* bSrc[2];
    #pragma unroll
    for (int c = 0; c < 2; c++)
        bSrc[c] = Tt + (size_t)(n0 + (wave * 2 + c) * 16 + rowInChunk) * NPAD + kOff8;

    const int wSlot = (((lane & 3) + ((lane >> 3) & 3)) & 3) * 8;
    int ldsWa[4], ldsWb[2];
    #pragma unroll
    for (int c = 0; c < 4; c++) ldsWa[c] = (wave * 4 + c) * 512 + rowInChunk * 32 + wSlot;
    #pragma unroll
    for (int c = 0; c < 2; c++) ldsWb[c] = (wave * 2 + c) * 512 + rowInChunk * 32 + wSlot;

    const int rSlot = ((((lane >> 4) + (((lane & 15) >> 1) & 3)) & 3)) * 8;
    const int rRow  = lane & 15;

    floatx4 acc[2][4][4];
    const floatx4 zero4 = {0.f, 0.f, 0.f, 0.f};
    #pragma unroll
    for (int t = 0; t < 2; t++)
        #pragma unroll
        for (int i = 0; i < 4; i++)
            #pragma unroll
            for (int j = 0; j < 4; j++) acc[t][i][j] = zero4;

    int4 aE[4], bE[2], aO[4], bO[2];   // staging (even/odd parity)

    #pragma unroll
    for (int c = 0; c < 4; c++) { aE[c] = *(const int4*)aSrc[c]; aSrc[c] += BK; }
    #pragma unroll
    for (int c = 0; c < 2; c++) { bE[c] = *(const int4*)bSrc[c]; bSrc[c] += BK; }
    #pragma unroll
    for (int c = 0; c < 4; c++) { aO[c] = *(const int4*)aSrc[c]; aSrc[c] += BK; }
    #pragma unroll
    for (int c = 0; c < 2; c++) { bO[c] = *(const int4*)bSrc[c]; bSrc[c] += BK; }

    #pragma unroll
    for (int c = 0; c < 4; c++) *(int4*)(&As[0][ldsWa[c]]) = aE[c];
    #pragma unroll
    for (int c = 0; c < 2; c++) *(int4*)(&Bs[0][ldsWb[c]]) = bE[c];
    wg_barrier_lds();

    for (int kt = 0; kt < kIters; kt += 2) {
        const bool more = (kt + 2 < kIters);

        {   // u = 0: compute stage kt from buf 0
            bf16x8 af[2][4], bfr[4];
            #pragma unroll
            for (int t = 0; t < 2; t++)
                #pragma unroll
                for (int mi = 0; mi < 4; mi++)
                    af[t][mi] = *(const bf16x8*)(&As[0][(t * 128 + wi * 64 + mi * 16 + rRow) * BK + rSlot]);
            #pragma unroll
            for (int nj = 0; nj < 4; nj++)
                bfr[nj] = *(const bf16x8*)(&Bs[0][(wj * 64 + nj * 16 + rRow) * BK + rSlot]);

            if (more) {
                #pragma unroll
                for (int c = 0; c < 4; c++) { aE[c] = *(const int4*)aSrc[c]; aSrc[c] += BK; }
                #pragma unroll
                for (int c = 0; c < 2; c++) { bE[c] = *(const int4*)bSrc[c]; bSrc[c] += BK; }
            }
            #pragma unroll
            for (int c = 0; c < 4; c++) *(int4*)(&As[1][ldsWa[c]]) = aO[c];
            #pragma unroll
            for (int c = 0; c < 2; c++) *(int4*)(&Bs[1][ldsWb[c]]) = bO[c];

            #pragma unroll
            for (int t = 0; t < 2; t++)
                #pragma unroll
                for (int mi = 0; mi < 4; mi++)
                    #pragma unroll
                    for (int nj = 0; nj < 4; nj++)
                        acc[t][mi][nj] = __builtin_amdgcn_mfma_f32_16x16x32_bf16(af[t][mi], bfr[nj], acc[t][mi][nj], 0, 0, 0);

            wg_barrier_lds();
        }

        {   // u = 1: compute stage kt+1 from buf 1
            bf16x8 af[2][4], bfr[4];
            #pragma unroll
            for (int t = 0; t < 2; t++)
                #pragma unroll
                for (int mi = 0; mi < 4; mi++)
                    af[t][mi] = *(const bf16x8*)(&As[1][(t * 128 + wi * 64 + mi * 16 + rRow) * BK + rSlot]);
            #pragma unroll
            for (int nj = 0; nj < 4; nj++)
                bfr[nj] = *(const bf16x8*)(&Bs[1][(wj * 64 + nj * 16 + rRow) * BK + rSlot]);

            if (more) {
                #pragma unroll
                for (int c = 0; c < 4; c++) { aO[c] = *(const int4*)aSrc[c]; aSrc[c] += BK; }
                #pragma unroll
                for (int c = 0; c < 2; c++) { bO[c] = *(const int4*)bSrc[c]; bSrc[c] += BK; }
                #pragma unroll
                for (int c = 0; c < 4; c++) *(int4*)(&As[0][ldsWa[c]]) = aE[c];
                #pragma unroll
                for (int c = 0; c < 2; c++) *(int4*)(&Bs[0][ldsWb[c]]) = bE[c];
            }

            #pragma unroll
            for (int t = 0; t < 2; t++)
                #pragma unroll
                for (int mi = 0; mi < 4; mi++)
                    #pragma unroll
                    for (int nj = 0; nj < 4; nj++)
                        acc[t][mi][nj] = __builtin_amdgcn_mfma_f32_16x16x32_bf16(af[t][mi], bfr[nj], acc[t][mi][nj], 0, 0, 0);

            wg_barrier_lds();
        }
    }

    // epilogue: C/D layout col=lane&15, row=(lane>>4)*4+reg
    #pragma unroll
    for (int t = 0; t < 2; t++) {
        #pragma unroll
        for (int mi = 0; mi < 4; mi++) {
            #pragma unroll
            for (int nj = 0; nj < 4; nj++) {
                #pragma unroll
                for (int r = 0; r < 4; r++) {
                    const int row = m0 + t * 128 + wi * 64 + mi * 16 + (lane >> 4) * 4 + r;
                    const int col = n0 + wj * 64 + nj * 16 + (lane & 15);
                    if (row < NREAL) {
                        const int c = col & 31, b = col >> 5;
                        const float v = elu_f(acc[t][mi][nj][r] + bias[c]);
                        outH[(size_t)b * KFC + row * 32 + c] = __float2bfloat16(v);
                    }
                }
            }
        }
    }
}

// ---------------------------------------------------------------------------
// convXA: x -> Xbf row-major [1024][896] bf16 (zero k-pad)
//         a -> Ar row-major [1024][896] bf16 (rows AND cols zero-padded)
// ---------------------------------------------------------------------------
__global__ void convXA(const float* __restrict__ x, const float* __restrict__ a,
                       __hip_bfloat16* __restrict__ Xbf, __hip_bfloat16* __restrict__ Ar)
{
    int idx = blockIdx.x * 256 + threadIdx.x;
    if (idx < BATCH * NPAD) {
        const int m = idx % NPAD, b = idx / NPAD;
        const float v = (m < NREAL) ? x[(size_t)b * NREAL + m] : 0.f;
        Xbf[idx] = __float2bfloat16(v);
    } else {
        idx -= BATCH * NPAD;
        if (idx < NPADM * NPAD) {
            const int m = idx % NPAD, n = idx / NPAD;
            const float v = (m < NREAL && n < NREAL) ? a[(size_t)n * NREAL + m] : 0.f;
            Ar[idx] = __float2bfloat16(v);
        }
    }
}

// wf1 [25088][512] fp32 -> Wt row-major bf16 [512][25088]
__global__ void convW(const float* __restrict__ wf1, __hip_bfloat16* __restrict__ Wt) {
    __shared__ float tile[32][33];
    const int k0 = blockIdx.x * 32, h0 = blockIdx.y * 32;
    const int tx = threadIdx.x, ty = threadIdx.y;  // (32,8)
    #pragma unroll
    for (int i = 0; i < 4; i++)
        tile[ty * 4 + i][tx] = wf1[(size_t)(k0 + ty * 4 + i) * HDIM + h0 + tx];
    __syncthreads();
    #pragma unroll
    for (int i = 0; i < 4; i++)
        Wt[(size_t)(h0 + ty * 4 + i) * KFC + k0 + tx] = __float2bfloat16(tile[tx][ty * 4 + i]);
}

// ---------------------------------------------------------------------------
// Layer-1 fused pointwise: reduce KS_G1 Y partials, then
// Tt[(b*32+c)][m] = sum_c1 elu(Y[b][m]*w1[c1]+b1[c1])*W2[c1][c]  (row-major)
// ---------------------------------------------------------------------------
__global__ void layer1_fuse(const float* __restrict__ Ypart,
                            const float* __restrict__ w1, const float* __restrict__ b1,
                            const float* __restrict__ w2,
                            __hip_bfloat16* __restrict__ Tt)
{
    __shared__ __align__(16) float sW2[C1D * C2D];
    __shared__ float sw1[C1D], sb1[C1D];
    const int tid = threadIdx.x;                 // 128 threads
    for (int i = tid; i < C1D * C2D; i += 128) sW2[i] = w2[i];
    if (tid < C1D) { sw1[tid] = w1[tid]; sb1[tid] = b1[tid]; }
    __syncthreads();

    const int m = blockIdx.x * 128 + tid;        // 0..895
    const int b = blockIdx.y;
    float y = 0.f;
    #pragma unroll
    for (int z = 0; z < KS_G1; z++)
        y += Ypart[(size_t)z * (BATCH * NPAD) + (size_t)b * NPAD + m];

    float h[C1D];
    #pragma unroll
    for (int c1 = 0; c1 < C1D; c1++) h[c1] = elu_f(y * sw1[c1] + sb1[c1]);

    float4 t4[8];
    #pragma unroll
    for (int q = 0; q < 8; q++) t4[q] = make_float4(0.f, 0.f, 0.f, 0.f);
    #pragma unroll
    for (int c1 = 0; c1 < C1D; c1++) {
        const float hv = h[c1];
        const float4* row = (const float4*)(sW2 + c1 * C2D);
        #pragma unroll
        for (int q = 0; q < 8; q++) {
            const float4 w = row[q];
            t4[q].x += hv * w.x; t4[q].y += hv * w.y;
            t4[q].z += hv * w.z; t4[q].w += hv * w.w;
        }
    }
    const float* tf = (const float*)t4;
    #pragma unroll
    for (int c = 0; c < C2D; c++)
        Tt[((size_t)(b * 32 + c)) * NPAD + m] = __float2bfloat16(tf[c]);
}

// ---------------------------------------------------------------------------
// fc1 reduce (split-K partials) + relu + fc2 + softmax, fused.
// ---------------------------------------------------------------------------
__global__ void fc2_softmax(const float* __restrict__ part, const float* __restrict__ bf1,
                            const float* __restrict__ wf2, const float* __restrict__ bf2,
                            float* __restrict__ out)
{
    __shared__ float sW[HDIM * NCLS];
    __shared__ float sb[NCLS];
    const int tid = threadIdx.x;                 // 256
    for (int i = tid; i < HDIM * NCLS; i += 256) sW[i] = wf2[i];
    if (tid < NCLS) sb[tid] = bf2[tid];
    __syncthreads();

    const int lane = tid & 63, wave = tid >> 6;
    const int b = blockIdx.x * 4 + wave;

    float acc[NCLS];
    #pragma unroll
    for (int c = 0; c < NCLS; c++) acc[c] = 0.f;
    #pragma unroll
    for (int q = 0; q < 8; q++) {
        const int h = q * 64 + lane;
        float hv = bf1[h];
        #pragma unroll
        for (int z = 0; z < KS_FC; z++)
            hv += part[(size_t)z * (BATCH * HDIM) + (size_t)b * HDIM + h];
        hv = hv > 0.f ? hv : 0.f;
        #pragma unroll
        for (int c = 0; c < NCLS; c++) acc[c] += hv * sW[h * NCLS + c];
    }
    #pragma unroll
    for (int c = 0; c < NCLS; c++) {
        #pragma unroll
        for (int off = 32; off >= 1; off >>= 1) acc[c] += __shfl_down(acc[c], off);
    }
    if (lane == 0) {
        float mx = -1e30f;
        #pragma unroll
        for (int c = 0; c < NCLS; c++) { acc[c] += sb[c]; mx = fmaxf(mx, acc[c]); }
        float e[NCLS], s = 0.f;
        #pragma unroll
        for (int c = 0; c < NCLS; c++) { e[c] = __expf(acc[c] - mx); s += e[c]; }
        const float inv = 1.f / s;
        #pragma unroll
        for (int c = 0; c < NCLS; c++) out[(size_t)b * NCLS + c] = e[c] * inv;
    }
}

// ---------------------------------------------------------------------------
// Workspace layout (peak ~113.8 MB; ws >= 119.3 MB proven)
//   h2f   [0,          51380224)  bf16 1024x25088  (written G3, read G4)
//     Ypart [0, 25690112) f32 7x1024x896 — overlay, dead before G3
//   Tt    [51380224,  110100480)  bf16 32768x896   (dead after G3)
//     Wt   [51380224, 77070336)   bf16 512x25088 — overlay after G3
//     part [77070336, 106430464)  f32 14x1024x512 — overlay after G3
//   Ar    [110100480, 111935488)  bf16 1024x896 (rows padded)
//   Xbf   [111935488, 113770496)  bf16 1024x896
// ---------------------------------------------------------------------------
extern "C" void kernel_launch(void* const* d_in, const int* in_sizes, int n_in,
                              void* d_out, int out_size, void* d_ws, size_t ws_size,
                              hipStream_t stream)
{
    const float* x   = (const float*)d_in[0];
    const float* a   = (const float*)d_in[1];
    const float* w1  = (const float*)d_in[2];
    const float* b1  = (const float*)d_in[3];
    const float* w2  = (const float*)d_in[4];
    const float* b2  = (const float*)d_in[5];
    const float* wf1 = (const float*)d_in[6];
    const float* bf1 = (const float*)d_in[7];
    const float* wf2 = (const float*)d_in[8];
    const float* bf2 = (const float*)d_in[9];
    float* out = (float*)d_out;

    char* ws = (char*)d_ws;
    __hip_bfloat16* h2f  = (__hip_bfloat16*)(ws + 0);
    float*          Ypart= (float*)(ws + 0);                  // overlay (pre-G3)
    __hip_bfloat16* Tt   = (__hip_bfloat16*)(ws + 51380224);
    __hip_bfloat16* Wt   = (__hip_bfloat16*)(ws + 51380224);  // overlay (post-G3)
    float*          part = (float*)(ws + 77070336);           // overlay (post-G3)
    __hip_bfloat16* Ar   = (__hip_bfloat16*)(ws + 110100480);
    __hip_bfloat16* Xbf  = (__hip_bfloat16*)(ws + 111935488);

    // 1) convert x and a (row-major bf16, zero-padded; Ar rows padded to 1024)
    convXA<<<(BATCH * NPAD + NPADM * NPAD + 255) / 256, 256, 0, stream>>>(x, a, Xbf, Ar);

    // 2) G1: Ypart[z][b][n] partials (split-K=7 -> 392 blocks, 4 iters)
    gemm_bt<<<dim3(NPAD / 128, BATCH / 128, KS_G1), 256, 0, stream>>>(
        Xbf, NPAD, Ar, NPAD, (NPAD / KS_G1) / BK, NPAD / KS_G1,
        (size_t)BATCH * NPAD, Ypart, NPAD);

    // 3) layer-1 pointwise + @W2 -> Tt row-major
    layer1_fuse<<<dim3(NPAD / 128, BATCH), 128, 0, stream>>>(Ypart, w1, b1, w2, Tt);

    // 4) G3 (m-doubled): h2 = elu(A @ T + b2)
    //    grid 256 x 4 = 1024 blocks, 28 iters, B LLC traffic halved (my 7->4)
    gemm_g3<<<dim3((BATCH * 32) / 128, NPADM / 256), 256, 0, stream>>>(
        Ar, Tt, NPAD / BK, h2f, b2);

    // 5) wf1 -> Wt row-major (into dead-Tt region)
    convW<<<dim3(KFC / 32, HDIM / 32), dim3(32, 8), 0, stream>>>(wf1, Wt);

    // 6) G4: fc1 partials, split-K=14 (448 blocks, 56 iters)
    gemm_bt<<<dim3(HDIM / 128, BATCH / 128, KS_FC), 256, 0, stream>>>(
        h2f, KFC, Wt, KFC, (KFC / KS_FC) / BK, KFC / KS_FC,
        (size_t)BATCH * HDIM, part, HDIM);

    // 7) fc1 reduce + relu + fc2 + softmax
    fc2_softmax<<<BATCH / 4, 256, 0, stream>>>(part, bf1, wf2, bf2, out);
}